// Round 10
// baseline (174.370 us; speedup 1.0000x reference)
//
#include <hip/hip_runtime.h>
#include <cstdint>
#include <cstddef>

#define LALPHA 0.2f
#define NEG_INF -9000000000000000.0f

constexpr int N_ = 1024;
constexpr int FIN = 128, FO = 64;
constexpr int BS = 32;
constexpr size_t H_ELEMS = (size_t)BS * N_ * FO;   // 2,097,152
constexpr size_t F_ELEMS = (size_t)BS * N_;        // 32,768
constexpr int SPLITK = 4;                          // j-range chunks (256 j each)

typedef __attribute__((ext_vector_type(8))) short short8;
typedef __attribute__((ext_vector_type(4))) float floatx4;
typedef __attribute__((ext_vector_type(4))) int   i32x4;
typedef __attribute__((ext_vector_type(4))) unsigned u32x4;

static __device__ __forceinline__ unsigned short f2bf(float x) {
    union { float f; unsigned u; } v; v.f = x;
    unsigned r = v.u + 0x7FFF + ((v.u >> 16) & 1);
    return (unsigned short)(r >> 16);
}
static __device__ __forceinline__ float bf2f_lo(unsigned u) {
    union { unsigned u; float f; } v; v.u = u << 16; return v.f;
}
static __device__ __forceinline__ float bf2f_hi(unsigned u) {
    union { unsigned u; float f; } v; v.u = u & 0xFFFF0000u; return v.f;
}

// ---------------- Kernel 1: h = x @ W, f1 = h@a1, f2 = h@a2 ----------------
__global__ __launch_bounds__(256) void k_h(
    const float* __restrict__ x, const float* __restrict__ W,
    const float* __restrict__ a, float* __restrict__ h,
    float* __restrict__ f1, float* __restrict__ f2)
{
    __shared__ float sW[FIN * FO];     // 32 KB
    __shared__ float sx[4][FIN];       // 2 KB
    const int t = threadIdx.x;
    for (int i = t; i < FIN * FO; i += 256) sW[i] = W[i];
    const size_t node0 = (size_t)blockIdx.x * 4;
    for (int i = t; i < 4 * FIN; i += 256) sx[i >> 7][i & 127] = x[node0 * FIN + i];
    __syncthreads();

    const int wave = t >> 6;
    const int lane = t & 63;
    const size_t node = node0 + wave;

    float acc = 0.f;
    #pragma unroll
    for (int f = 0; f < FIN; ++f)
        acc = fmaf(sx[wave][f], sW[f * FO + lane], acc);

    h[node * FO + lane] = acc;

    float v1 = acc * a[lane];
    float v2 = acc * a[FO + lane];
    #pragma unroll
    for (int off = 32; off > 0; off >>= 1) {
        v1 += __shfl_xor(v1, off);
        v2 += __shfl_xor(v2, off);
    }
    if (lane == 0) { f1[node] = v1; f2[node] = v2; }
}

// ------------- Kernel 2: transpose+convert h -> hT bf16 [bs][o][j] ----------
__global__ __launch_bounds__(256) void k_tr(
    const float* __restrict__ h, unsigned short* __restrict__ hT)
{
    __shared__ float lt[64][65];
    const int bs = blockIdx.x >> 4;
    const int n0 = (blockIdx.x & 15) * 64;
    const int t = threadIdx.x;
    const float* hb = h + ((size_t)bs << 16) + ((size_t)n0 << 6);
    #pragma unroll
    for (int k = 0; k < 4; ++k) {
        const int r = (t >> 4) + k * 16;
        const int c = (t & 15) * 4;
        const float4 v = *(const float4*)(hb + ((size_t)r << 6) + c);
        lt[r][c] = v.x; lt[r][c + 1] = v.y; lt[r][c + 2] = v.z; lt[r][c + 3] = v.w;
    }
    __syncthreads();
    const int o = t >> 2, ch = (t & 3) * 16;
    unsigned short tmp[16];
    #pragma unroll
    for (int q = 0; q < 16; ++q) tmp[q] = f2bf(lt[ch + q][o]);
    unsigned short* dst = hT + ((size_t)bs << 16) + ((size_t)o << 10) + n0 + ch;
    *(uint4*)dst = *(uint4*)tmp;
    *(uint4*)(dst + 8) = *(uint4*)(tmp + 8);
}

// ---- Kernel 3: fused adjf + softmax-over-s + MFMA att@h (split-K) ---------
// block: (kk, b, 16-row i-tile); j range [kk*256, kk*256+256), 4 jt of 64.
// Per-jt order: issue_loads(jt) -> mfma(jt-1) -> softmax(jt); ONE barrier/jt.
// The jt Adj loads stay in flight across the whole MFMA phase.
__global__ __launch_bounds__(256, 4) void k_av(
    const int* __restrict__ Adj, const float* __restrict__ f1,
    const float* __restrict__ f2, const unsigned short* __restrict__ hT,
    unsigned short* __restrict__ part, float* __restrict__ out_adj)
{
    __shared__ __align__(16) unsigned short att[2][8][16][64];   // 32 KB

    const int bid   = blockIdx.x;
    const int kk    = bid >> 8;          // 0..3
    const int b     = (bid >> 6) & 3;
    const int i0    = (bid & 63) * 16;
    const int t     = threadIdx.x;

    const int p_jj = (t & 15) * 4;
    const int p_ii = t >> 4;
    const int gi   = i0 + p_ii;

    const int w  = t >> 6;
    const int l  = t & 63;
    const int fr = l & 15;
    const int fg = l >> 4;

    float fi[8];
    #pragma unroll
    for (int s = 0; s < 8; ++s) fi[s] = f1[(size_t)(b * 8 + s) * N_ + gi];

    floatx4 acc[2][4];
    #pragma unroll
    for (int si = 0; si < 2; ++si)
        #pragma unroll
        for (int n = 0; n < 4; ++n)
            acc[si][n] = (floatx4){0.f, 0.f, 0.f, 0.f};

    i32x4 ad[8];

    auto issue_loads = [&](int jt) {
        const int j0 = (kk * 4 + jt) * 64;
        #pragma unroll
        for (int s = 0; s < 8; ++s) {
            const size_t aoff = ((size_t)(b * 8 + s) << 20) + ((size_t)gi << 10) + (size_t)(j0 + p_jj);
            ad[s] = __builtin_nontemporal_load((const i32x4*)(Adj + aoff));
        }
    };

    auto softmax_store = [&](int jt, int pb) {
        const int j0 = (kk * 4 + jt) * 64;
        float ev[8][4];
        #pragma unroll
        for (int s = 0; s < 8; ++s) {
            const size_t aoff = ((size_t)(b * 8 + s) << 20) + ((size_t)gi << 10) + (size_t)(j0 + p_jj);
            floatx4 o;
            o.x = (float)ad[s].x; o.y = (float)ad[s].y;
            o.z = (float)ad[s].z; o.w = (float)ad[s].w;
            __builtin_nontemporal_store(o, (floatx4*)(out_adj + aoff));
            const float4 fj = *(const float4*)(f2 + (size_t)(b * 8 + s) * N_ + j0 + p_jj);
            const float v0 = fi[s] + fj.x, v1 = fi[s] + fj.y;
            const float v2 = fi[s] + fj.z, v3 = fi[s] + fj.w;
            ev[s][0] = ad[s].x > 0 ? (v0 >= 0.f ? v0 : LALPHA * v0) : NEG_INF;
            ev[s][1] = ad[s].y > 0 ? (v1 >= 0.f ? v1 : LALPHA * v1) : NEG_INF;
            ev[s][2] = ad[s].z > 0 ? (v2 >= 0.f ? v2 : LALPHA * v2) : NEG_INF;
            ev[s][3] = ad[s].w > 0 ? (v3 >= 0.f ? v3 : LALPHA * v3) : NEG_INF;
        }
        #pragma unroll
        for (int q = 0; q < 4; ++q) {
            float m = NEG_INF;
            #pragma unroll
            for (int s = 0; s < 8; ++s) m = fmaxf(m, ev[s][q]);
            float p[8], den = 0.f;
            #pragma unroll
            for (int s = 0; s < 8; ++s) { p[s] = __expf(ev[s][q] - m); den += p[s]; }
            const float r = 1.0f / den;
            #pragma unroll
            for (int s = 0; s < 8; ++s) ev[s][q] = p[s] * r;
        }
        const int chs  = (p_jj >> 3) ^ (p_ii & 7);
        const int boff = chs * 16 + (p_jj & 7) * 2;
        #pragma unroll
        for (int s = 0; s < 8; ++s) {
            ushort4 wv;
            wv.x = f2bf(ev[s][0]); wv.y = f2bf(ev[s][1]);
            wv.z = f2bf(ev[s][2]); wv.w = f2bf(ev[s][3]);
            *(ushort4*)((char*)&att[pb][s][p_ii][0] + boff) = wv;
        }
    };

    auto do_mfma = [&](int jt, int pb) {
        const int j0 = (kk * 4 + jt) * 64;
        __builtin_amdgcn_s_setprio(1);
        #pragma unroll
        for (int ks = 0; ks < 2; ++ks) {
            short8 af[2];
            #pragma unroll
            for (int si = 0; si < 2; ++si) {
                const int s = 2 * w + si;
                const int c = (ks * 4 + fg) ^ (fr & 7);
                af[si] = *(const short8*)((const char*)&att[pb][s][fr][0] + c * 16);
            }
            #pragma unroll
            for (int n = 0; n < 4; ++n) {
                #pragma unroll
                for (int si = 0; si < 2; ++si) {
                    const int bs = b * 8 + 2 * w + si;
                    const short8 bf = *(const short8*)(
                        hT + ((size_t)bs << 16) + (size_t)(n * 16 + fr) * N_ + j0 + ks * 32 + fg * 8);
                    acc[si][n] = __builtin_amdgcn_mfma_f32_16x16x32_bf16(af[si], bf, acc[si][n], 0, 0, 0);
                }
            }
        }
        __builtin_amdgcn_s_setprio(0);
    };

    // prologue
    issue_loads(0);
    softmax_store(0, 0);
    __syncthreads();
    // steady state: loads(jt) in flight across mfma(jt-1)
    #pragma unroll
    for (int jt = 1; jt < 4; ++jt) {
        issue_loads(jt);
        do_mfma(jt - 1, (jt - 1) & 1);
        softmax_store(jt, jt & 1);
        __syncthreads();
    }
    do_mfma(3, 1);

    // ---- epilogue: write bf16 partials (NT: read exactly once by k_comb) ---
    #pragma unroll
    for (int si = 0; si < 2; ++si) {
        const int bs = b * 8 + 2 * w + si;
        #pragma unroll
        for (int n = 0; n < 4; ++n) {
            #pragma unroll
            for (int r = 0; r < 4; ++r) {
                __builtin_nontemporal_store(f2bf(acc[si][n][r]),
                    part + (size_t)kk * H_ELEMS + ((size_t)bs << 16)
                         + (size_t)(i0 + fg * 4 + r) * FO + n * 16 + fr);
            }
        }
    }
}

// ---------------- Kernel 4: combine 4 bf16 partials + elu -------------------
__global__ __launch_bounds__(256) void k_comb(
    const unsigned short* __restrict__ part, float* __restrict__ out_h)
{
    const size_t idx = ((size_t)blockIdx.x * 256 + threadIdx.x) * 8;
    float acc[8] = {0.f,0.f,0.f,0.f,0.f,0.f,0.f,0.f};
    #pragma unroll
    for (int p = 0; p < SPLITK; ++p) {
        const u32x4 v = __builtin_nontemporal_load(
            (const u32x4*)(part + (size_t)p * H_ELEMS + idx));
        acc[0] += bf2f_lo(v.x); acc[1] += bf2f_hi(v.x);
        acc[2] += bf2f_lo(v.y); acc[3] += bf2f_hi(v.y);
        acc[4] += bf2f_lo(v.z); acc[5] += bf2f_hi(v.z);
        acc[6] += bf2f_lo(v.w); acc[7] += bf2f_hi(v.w);
    }
    floatx4 r0, r1;
    r0.x = acc[0] > 0.f ? acc[0] : expm1f(acc[0]);
    r0.y = acc[1] > 0.f ? acc[1] : expm1f(acc[1]);
    r0.z = acc[2] > 0.f ? acc[2] : expm1f(acc[2]);
    r0.w = acc[3] > 0.f ? acc[3] : expm1f(acc[3]);
    r1.x = acc[4] > 0.f ? acc[4] : expm1f(acc[4]);
    r1.y = acc[5] > 0.f ? acc[5] : expm1f(acc[5]);
    r1.z = acc[6] > 0.f ? acc[6] : expm1f(acc[6]);
    r1.w = acc[7] > 0.f ? acc[7] : expm1f(acc[7]);
    __builtin_nontemporal_store(r0, (floatx4*)(out_h + idx));
    __builtin_nontemporal_store(r1, (floatx4*)(out_h + idx + 4));
}

extern "C" void kernel_launch(void* const* d_in, const int* in_sizes, int n_in,
                              void* d_out, int out_size, void* d_ws, size_t ws_size,
                              hipStream_t stream)
{
    const float* x   = (const float*)d_in[0];
    const int*   Adj = (const int*)d_in[1];
    const float* W   = (const float*)d_in[2];
    const float* a   = (const float*)d_in[3];

    float* out = (float*)d_out;
    float* ws  = (float*)d_ws;

    // ws layout: f1 | f2 | hT(bf16) | h(f32) / part(bf16, aliased over h)
    float* f1 = ws;                                         // 32,768 f32
    float* f2 = f1 + F_ELEMS;                               // 32,768 f32
    unsigned short* hT = (unsigned short*)(f2 + F_ELEMS);   // H_ELEMS bf16 (4MB)
    float* h = (float*)(hT + H_ELEMS);                      // 8 MB f32 (dead after k_tr)
    unsigned short* part = (unsigned short*)h;              // 4*H bf16 = 16.8 MB

    float* out_h   = out;                                   // elu(h_prime)
    float* out_adj = out + H_ELEMS;                         // Adj as float

    hipLaunchKernelGGL(k_h,    dim3(BS * N_ / 4),           dim3(256), 0, stream, x, W, a, h, f1, f2);
    hipLaunchKernelGGL(k_tr,   dim3(BS * 16),               dim3(256), 0, stream, h, hT);
    hipLaunchKernelGGL(k_av,   dim3(SPLITK * 4 * 64),       dim3(256), 0, stream, Adj, f1, f2, hT, part, out_adj);
    hipLaunchKernelGGL(k_comb, dim3((int)(H_ELEMS / 2048)), dim3(256), 0, stream, part, out_h);
}

// Round 11
// 146.690 us; speedup vs baseline: 1.1887x; 1.1887x over previous
//
#include <hip/hip_runtime.h>
#include <cstdint>
#include <cstddef>

#define LALPHA 0.2f
#define NEG_INF -9000000000000000.0f

constexpr int N_ = 1024;
constexpr int FIN = 128, FO = 64;
constexpr int BS = 32;
constexpr size_t H_ELEMS = (size_t)BS * N_ * FO;   // 2,097,152
constexpr size_t F_ELEMS = (size_t)BS * N_;        // 32,768
constexpr size_t M_ELEMS = (size_t)4 * N_ * N_;    // 4,194,304

typedef __attribute__((ext_vector_type(8))) short short8;
typedef __attribute__((ext_vector_type(4))) float floatx4;
typedef __attribute__((ext_vector_type(4))) int   i32x4;

static __device__ __forceinline__ unsigned short f2bf(float x) {
    union { float f; unsigned u; } v; v.f = x;
    unsigned r = v.u + 0x7FFF + ((v.u >> 16) & 1);
    return (unsigned short)(r >> 16);
}
static __device__ __forceinline__ float bf2f(unsigned short u) {
    union { unsigned u; float f; } v; v.u = (unsigned)u << 16; return v.f;
}

// ---------------- Kernel 1: h = x @ W, f1 = h@a1, f2 = h@a2 ----------------
__global__ __launch_bounds__(256) void k_h(
    const float* __restrict__ x, const float* __restrict__ W,
    const float* __restrict__ a, float* __restrict__ h,
    float* __restrict__ f1, float* __restrict__ f2)
{
    __shared__ float sW[FIN * FO];     // 32 KB
    __shared__ float sx[4][FIN];       // 2 KB
    const int t = threadIdx.x;
    for (int i = t; i < FIN * FO; i += 256) sW[i] = W[i];
    const size_t node0 = (size_t)blockIdx.x * 4;
    for (int i = t; i < 4 * FIN; i += 256) sx[i >> 7][i & 127] = x[node0 * FIN + i];
    __syncthreads();

    const int wave = t >> 6;
    const int lane = t & 63;
    const size_t node = node0 + wave;

    float acc = 0.f;
    #pragma unroll
    for (int f = 0; f < FIN; ++f)
        acc = fmaf(sx[wave][f], sW[f * FO + lane], acc);

    h[node * FO + lane] = acc;

    float v1 = acc * a[lane];
    float v2 = acc * a[FO + lane];
    #pragma unroll
    for (int off = 32; off > 0; off >>= 1) {
        v1 += __shfl_xor(v1, off);
        v2 += __shfl_xor(v2, off);
    }
    if (lane == 0) { f1[node] = v1; f2[node] = v2; }
}

// ------------- Kernel 2: transpose+convert h -> hT bf16 [bs][o][j] ----------
__global__ __launch_bounds__(256) void k_tr(
    const float* __restrict__ h, unsigned short* __restrict__ hT)
{
    __shared__ float lt[64][65];
    const int bs = blockIdx.x >> 4;
    const int n0 = (blockIdx.x & 15) * 64;
    const int t = threadIdx.x;
    const float* hb = h + ((size_t)bs << 16) + ((size_t)n0 << 6);
    #pragma unroll
    for (int k = 0; k < 4; ++k) {
        const int r = (t >> 4) + k * 16;
        const int c = (t & 15) * 4;
        const float4 v = *(const float4*)(hb + ((size_t)r << 6) + c);
        lt[r][c] = v.x; lt[r][c + 1] = v.y; lt[r][c + 2] = v.z; lt[r][c + 3] = v.w;
    }
    __syncthreads();
    const int o = t >> 2, ch = (t & 3) * 16;
    unsigned short tmp[16];
    #pragma unroll
    for (int q = 0; q < 16; ++q) tmp[q] = f2bf(lt[ch + q][o]);
    unsigned short* dst = hT + ((size_t)bs << 16) + ((size_t)o << 10) + n0 + ch;
    *(uint4*)dst = *(uint4*)tmp;
    *(uint4*)(dst + 8) = *(uint4*)(tmp + 8);
}

// ---- Kernel 1b: adjf copy + packed mask + softmax stats mld (bf16) --------
// Streaming, barrier-free. Adj via PLAIN loads (L3 retention across replays);
// adjf via NT stores (never re-read); packed/mld plain stores (re-read by k_av).
__global__ __launch_bounds__(256) void k_front(
    const int* __restrict__ Adj, const float* __restrict__ f1,
    const float* __restrict__ f2, float* __restrict__ adjf,
    unsigned char* __restrict__ packed, unsigned short* __restrict__ mldb)
{
    const size_t tid = (size_t)blockIdx.x * 256 + threadIdx.x;  // [b][i][j4]
    const int j4 = (int)(tid & 255) * 4;
    const int i  = (int)((tid >> 8) & 1023);
    const int b  = (int)(tid >> 18);

    i32x4 ad[8];
    #pragma unroll
    for (int s = 0; s < 8; ++s) {
        const size_t off = ((size_t)(b * 8 + s) << 20) + ((size_t)i << 10) + (size_t)j4;
        ad[s] = *(const i32x4*)(Adj + off);
    }
    float fi[8];
    #pragma unroll
    for (int s = 0; s < 8; ++s) fi[s] = f1[(size_t)(b * 8 + s) * N_ + i];

    float ev[8][4];
    unsigned b0 = 0, b1 = 0, b2 = 0, b3 = 0;
    #pragma unroll
    for (int s = 0; s < 8; ++s) {
        const size_t off = ((size_t)(b * 8 + s) << 20) + ((size_t)i << 10) + (size_t)j4;
        floatx4 o;
        o.x = (float)ad[s].x; o.y = (float)ad[s].y;
        o.z = (float)ad[s].z; o.w = (float)ad[s].w;
        __builtin_nontemporal_store(o, (floatx4*)(adjf + off));
        const float4 fj = *(const float4*)(f2 + (size_t)(b * 8 + s) * N_ + j4);
        const float v0 = fi[s] + fj.x, v1 = fi[s] + fj.y;
        const float v2 = fi[s] + fj.z, v3 = fi[s] + fj.w;
        ev[s][0] = ad[s].x > 0 ? (v0 >= 0.f ? v0 : LALPHA * v0) : NEG_INF;
        ev[s][1] = ad[s].y > 0 ? (v1 >= 0.f ? v1 : LALPHA * v1) : NEG_INF;
        ev[s][2] = ad[s].z > 0 ? (v2 >= 0.f ? v2 : LALPHA * v2) : NEG_INF;
        ev[s][3] = ad[s].w > 0 ? (v3 >= 0.f ? v3 : LALPHA * v3) : NEG_INF;
        b0 |= (unsigned)(ad[s].x > 0) << s;
        b1 |= (unsigned)(ad[s].y > 0) << s;
        b2 |= (unsigned)(ad[s].z > 0) << s;
        b3 |= (unsigned)(ad[s].w > 0) << s;
    }
    ushort4 ml;
    unsigned short* mlp = (unsigned short*)&ml;
    #pragma unroll
    for (int q = 0; q < 4; ++q) {
        float m = NEG_INF;
        #pragma unroll
        for (int s = 0; s < 8; ++s) m = fmaxf(m, ev[s][q]);
        float den = 0.f;
        #pragma unroll
        for (int s = 0; s < 8; ++s) den += __expf(ev[s][q] - m);
        mlp[q] = f2bf(m + __logf(den));
    }
    const size_t moff = ((size_t)b << 20) + ((size_t)i << 10) + (size_t)j4;
    *(ushort4*)(mldb + moff) = ml;
    uchar4 pk;
    pk.x = (unsigned char)b0; pk.y = (unsigned char)b1;
    pk.z = (unsigned char)b2; pk.w = (unsigned char)b3;
    *(uchar4*)(packed + moff) = pk;
}

// ---- Kernel 3: wave-autonomous att@h GEMM, A-frag computed in registers ---
// block = (bs, 16-row i-tile), 4 waves = 4 j-quarters. NO barriers in the hot
// loop, no LDS staging: each lane computes its own 8 A-frag att values
// (att = exp(leaky(fi+fj) - mld), mask bit -> 0, all-masked col -> 1/8),
// B-frags stream from L2-resident hT. One LDS reduce at the end + elu.
__global__ __launch_bounds__(256) void k_av(
    const unsigned char* __restrict__ packed, const float* __restrict__ f1,
    const float* __restrict__ f2, const unsigned short* __restrict__ mldb,
    const unsigned short* __restrict__ hT, float* __restrict__ out_h)
{
    __shared__ float red[4][4][16][17];   // [q][n][row][col], padded: 17.4 KB

    const int bid   = blockIdx.x;
    const int bs    = bid >> 6;          // 0..31
    const int i0    = (bid & 63) * 16;
    const int t     = threadIdx.x;
    const int q     = t >> 6;            // j-quarter
    const int l     = t & 63;
    const int fr    = l & 15;            // A row / B col / C col
    const int fg    = l >> 4;            // k-group / C row-group
    const int b     = bs >> 3;
    const int s     = bs & 7;

    const float fi = f1[(size_t)bs * N_ + i0 + fr];
    const unsigned char*  pkrow = packed + ((size_t)b << 20) + (size_t)(i0 + fr) * N_;
    const unsigned short* mlrow = mldb   + ((size_t)b << 20) + (size_t)(i0 + fr) * N_;
    const float*          fjrow = f2 + (size_t)bs * N_;
    const unsigned short* hrow  = hT + ((size_t)bs << 16);

    floatx4 acc[4];
    #pragma unroll
    for (int n = 0; n < 4; ++n) acc[n] = (floatx4){0.f, 0.f, 0.f, 0.f};

    #pragma unroll
    for (int st = 0; st < 8; ++st) {
        const int jb = q * 256 + st * 32 + fg * 8;

        const uint2 pk8 = *(const uint2*)(pkrow + jb);
        const short8 ml8 = *(const short8*)(const void*)(mlrow + jb);
        const float4 fj0 = *(const float4*)(fjrow + jb);
        const float4 fj1 = *(const float4*)(fjrow + jb + 4);

        short8 aw;
        #pragma unroll
        for (int e = 0; e < 8; ++e) {
            const unsigned pe = (e < 4 ? (pk8.x >> (8 * e)) : (pk8.y >> (8 * (e - 4)))) & 0xFFu;
            const float fj = e < 4 ? ((const float*)&fj0)[e] : ((const float*)&fj1)[e - 4];
            const float v  = fi + fj;
            const float lk = v >= 0.f ? v : LALPHA * v;
            const float ml = bf2f((unsigned short)ml8[e]);
            float att;
            if (pe == 0)            att = 0.125f;
            else if ((pe >> s) & 1) att = __expf(lk - ml);
            else                    att = 0.f;
            aw[e] = (short)f2bf(att);
        }
        #pragma unroll
        for (int n = 0; n < 4; ++n) {
            const short8 bf = *(const short8*)(const void*)(
                hrow + (size_t)(n * 16 + fr) * N_ + jb);
            acc[n] = __builtin_amdgcn_mfma_f32_16x16x32_bf16(aw, bf, acc[n], 0, 0, 0);
        }
    }

    // ---- reduce 4 j-quarter partials in LDS, elu, store ----
    #pragma unroll
    for (int n = 0; n < 4; ++n)
        #pragma unroll
        for (int r = 0; r < 4; ++r)
            red[q][n][fg * 4 + r][fr] = acc[n][r];
    __syncthreads();

    // wave q handles output n-tile q
    #pragma unroll
    for (int r = 0; r < 4; ++r) {
        const int row = fg * 4 + r;
        const float sum = red[0][q][row][fr] + red[1][q][row][fr]
                        + red[2][q][row][fr] + red[3][q][row][fr];
        const float ev = sum > 0.f ? sum : expm1f(sum);
        __builtin_nontemporal_store(ev,
            out_h + ((size_t)bs << 16) + (size_t)(i0 + row) * FO + q * 16 + fr);
    }
}

extern "C" void kernel_launch(void* const* d_in, const int* in_sizes, int n_in,
                              void* d_out, int out_size, void* d_ws, size_t ws_size,
                              hipStream_t stream)
{
    const float* x   = (const float*)d_in[0];
    const int*   Adj = (const int*)d_in[1];
    const float* W   = (const float*)d_in[2];
    const float* a   = (const float*)d_in[3];

    float* out = (float*)d_out;
    float* ws  = (float*)d_ws;

    // ws layout: f1 | f2 | hT(bf16 4MB) | packed(4.2MB) | mld(bf16 8.4MB) | h(8MB)
    // Total ~24.9 MB.
    float* f1 = ws;                                          // 32K f32
    float* f2 = f1 + F_ELEMS;                                // 32K f32
    unsigned short* hT = (unsigned short*)(f2 + F_ELEMS);    // H_ELEMS bf16
    unsigned char* packed = (unsigned char*)(hT + H_ELEMS);  // M_ELEMS u8
    unsigned short* mldb = (unsigned short*)(packed + M_ELEMS); // M_ELEMS bf16
    float* h = (float*)(mldb + M_ELEMS);                     // H_ELEMS f32

    float* out_h   = out;                                    // elu(h_prime)
    float* out_adj = out + H_ELEMS;                          // Adj as float

    hipLaunchKernelGGL(k_h,     dim3(BS * N_ / 4), dim3(256), 0, stream, x, W, a, h, f1, f2);
    hipLaunchKernelGGL(k_tr,    dim3(BS * 16),     dim3(256), 0, stream, h, hT);
    hipLaunchKernelGGL(k_front, dim3(4096),        dim3(256), 0, stream, Adj, f1, f2, out_adj, packed, mldb);
    hipLaunchKernelGGL(k_av,    dim3(BS * 64),     dim3(256), 0, stream, packed, f1, f2, mldb, hT, out_h);
}